// Round 1
// baseline (135.679 us; speedup 1.0000x reference)
//
#include <hip/hip_runtime.h>

typedef _Float16 half8 __attribute__((ext_vector_type(8)));
typedef _Float16 half4_t __attribute__((ext_vector_type(4)));
typedef float floatx4 __attribute__((ext_vector_type(4)));

static constexpr int NB  = 32;    // batches
static constexpr int NP  = 4096;  // points per batch
static constexpr int DD  = 128;   // dim
static constexpr int KC  = 64;    // clusters
static constexpr int TN  = 64;    // points per tile
static constexpr int TPB = 4;     // tiles per block
static constexpr int SXP = 136;   // sx / sclo pitch (halfwords), 16B-aligned rows
static constexpr int STP = 72;    // sxt / sat pitch (halfwords), 16B-aligned rows

#define ALPHA_  100.0f
#define LOG2E_  1.44269504088896f

// Phase 1: per (batch, 256-point group): distances -> softmax -> partial vlad
__global__ __launch_bounds__(256, 2)
void vlad_phase1(const float* __restrict__ xg, const float* __restrict__ cg,
                 float* __restrict__ vlad, float* __restrict__ colsum)
{
    __shared__ __align__(16) _Float16 sx[TN][SXP];    // x tile fp16 [n][d]
    __shared__ __align__(16) _Float16 sxt[DD][STP];   // x tile fp16 transposed [d][n]
    __shared__ __align__(16) _Float16 sat[KC][STP];   // softmax a, transposed [k][n]
    __shared__ __align__(16) _Float16 sclo[KC][SXP];  // centroid lo residual fp16 [k][d]
    __shared__ float sx2[TN];
    __shared__ float sc2[KC];

    const int tid  = threadIdx.x;
    const int lane = tid & 63;
    const int w    = tid >> 6;    // wave 0..3
    const int l15  = lane & 15;
    const int quad = lane >> 4;
    const int b    = blockIdx.y;
    const float* xb = xg + (size_t)b * NP * DD;

    // ---- centroid prep: hi-frags in registers, lo tile + c2 in LDS ----
    half8 chi[4][4]; // [mt][ks]
#pragma unroll
    for (int mt = 0; mt < 4; ++mt)
#pragma unroll
        for (int ks = 0; ks < 4; ++ks) {
            const float* p = cg + (mt*16 + l15)*DD + ks*32 + quad*8;
            float4 a  = *(const float4*)p;
            float4 bb = *(const float4*)(p + 4);
            half8 h;
            h[0]=(_Float16)a.x;  h[1]=(_Float16)a.y;  h[2]=(_Float16)a.z;  h[3]=(_Float16)a.w;
            h[4]=(_Float16)bb.x; h[5]=(_Float16)bb.y; h[6]=(_Float16)bb.z; h[7]=(_Float16)bb.w;
            chi[mt][ks] = h;
        }
    {
        int k = tid >> 2, qq = tid & 3;
        const float* rp = cg + k*DD + qq*32;
        float c2p = 0.f;
#pragma unroll
        for (int j = 0; j < 8; ++j) {
            float4 v = *(const float4*)(rp + j*4);
            c2p += v.x*v.x + v.y*v.y + v.z*v.z + v.w*v.w;
            half4_t lo;
            lo[0] = (_Float16)(v.x - (float)(_Float16)v.x);
            lo[1] = (_Float16)(v.y - (float)(_Float16)v.y);
            lo[2] = (_Float16)(v.z - (float)(_Float16)v.z);
            lo[3] = (_Float16)(v.w - (float)(_Float16)v.w);
            *(half4_t*)&sclo[k][(qq*8 + j)*4] = lo;
        }
        c2p += __shfl_xor(c2p, 1);
        c2p += __shfl_xor(c2p, 2);
        if (qq == 0) sc2[k] = c2p;
    }

    floatx4 acc2[8]; // vlad partial [nt] : rows k = w*16+quad*4+reg, cols d = nt*16+l15
#pragma unroll
    for (int i = 0; i < 8; ++i) acc2[i] = (floatx4){0.f, 0.f, 0.f, 0.f};
    float csreg[4][4];
#pragma unroll
    for (int mt = 0; mt < 4; ++mt)
#pragma unroll
        for (int r = 0; r < 4; ++r) csreg[mt][r] = 0.f;

    for (int tt = 0; tt < TPB; ++tt) {
        const int n0 = (blockIdx.x * TPB + tt) * TN;

        // ---- stage x tile (fp16) + row sums of squares (fp32) ----
#pragma unroll
        for (int i = 0; i < 4; ++i) {
            int u = i*256 + tid;
            int n = u >> 4, d8 = u & 15;
            const float* p = xb + (size_t)(n0 + n)*DD + d8*8;
            float4 a  = *(const float4*)p;
            float4 bb = *(const float4*)(p + 4);
            half8 h;
            h[0]=(_Float16)a.x;  h[1]=(_Float16)a.y;  h[2]=(_Float16)a.z;  h[3]=(_Float16)a.w;
            h[4]=(_Float16)bb.x; h[5]=(_Float16)bb.y; h[6]=(_Float16)bb.z; h[7]=(_Float16)bb.w;
            *(half8*)&sx[n][d8*8] = h;
            float s = a.x*a.x + a.y*a.y + a.z*a.z + a.w*a.w
                    + bb.x*bb.x + bb.y*bb.y + bb.z*bb.z + bb.w*bb.w;
            s += __shfl_xor(s, 1); s += __shfl_xor(s, 2);
            s += __shfl_xor(s, 4); s += __shfl_xor(s, 8);
            if ((lane & 15) == 0) sx2[n] = s;
        }
        __syncthreads();

        // ---- GEMM1: S^T[k][n] = C · x^T  (c split hi+lo, x fp16) ----
        floatx4 acc1[4];
#pragma unroll
        for (int mt = 0; mt < 4; ++mt) acc1[mt] = (floatx4){0.f, 0.f, 0.f, 0.f};
#pragma unroll
        for (int ks = 0; ks < 4; ++ks) {
            half8 xf = *(const half8*)&sx[w*16 + l15][ks*32 + quad*8];
#pragma unroll
            for (int mt = 0; mt < 4; ++mt) {
                half8 cl = *(const half8*)&sclo[mt*16 + l15][ks*32 + quad*8];
                acc1[mt] = __builtin_amdgcn_mfma_f32_16x16x32_f16(chi[mt][ks], xf, acc1[mt], 0, 0, 0);
                acc1[mt] = __builtin_amdgcn_mfma_f32_16x16x32_f16(cl,          xf, acc1[mt], 0, 0, 0);
            }
        }

        // ---- softmax over clusters for this lane's column (point) ----
        const int n_loc = w*16 + l15;
        float x2v = sx2[n_loc];
        float dist[4][4];
#pragma unroll
        for (int mt = 0; mt < 4; ++mt) {
            floatx4 c2v = *(const floatx4*)&sc2[mt*16 + quad*4];
#pragma unroll
            for (int r = 0; r < 4; ++r) {
                float d2 = x2v + c2v[r] - 2.f*acc1[mt][r];
                dist[mt][r] = sqrtf(fmaxf(d2, 0.f));
            }
        }
        float dmin = dist[0][0];
#pragma unroll
        for (int mt = 0; mt < 4; ++mt)
#pragma unroll
            for (int r = 0; r < 4; ++r) dmin = fminf(dmin, dist[mt][r]);
        dmin = fminf(dmin, __shfl_xor(dmin, 16));
        dmin = fminf(dmin, __shfl_xor(dmin, 32));
        float pv[4][4];
        float psum = 0.f;
#pragma unroll
        for (int mt = 0; mt < 4; ++mt)
#pragma unroll
            for (int r = 0; r < 4; ++r) {
                float e = exp2f((dmin - dist[mt][r]) * (ALPHA_ * LOG2E_));
                pv[mt][r] = e; psum += e;
            }
        psum += __shfl_xor(psum, 16);
        psum += __shfl_xor(psum, 32);
        float invs = 1.0f / psum;  // psum >= 1
#pragma unroll
        for (int mt = 0; mt < 4; ++mt)
#pragma unroll
            for (int r = 0; r < 4; ++r) {
                float a = pv[mt][r] * invs;
                csreg[mt][r] += a;
                sat[mt*16 + quad*4 + r][n_loc] = (_Float16)a;
            }

        // ---- transpose x tile into sxt[d][n] ----
        {
            const int l5  = lane & 31;
            const int nn  = 2 * l5;
            const int dhi = (lane >> 5) * 16;
#pragma unroll
            for (int j = 0; j < 4; ++j) {
                int d4 = (w + 4*j + dhi) * 4;  // row group of 4 d's
                ushort4 lo = *(const ushort4*)&sx[nn][d4];
                ushort4 hi = *(const ushort4*)&sx[nn + 1][d4];
                *(unsigned*)&sxt[d4 + 0][nn] = (unsigned)lo.x | ((unsigned)hi.x << 16);
                *(unsigned*)&sxt[d4 + 1][nn] = (unsigned)lo.y | ((unsigned)hi.y << 16);
                *(unsigned*)&sxt[d4 + 2][nn] = (unsigned)lo.z | ((unsigned)hi.z << 16);
                *(unsigned*)&sxt[d4 + 3][nn] = (unsigned)lo.w | ((unsigned)hi.w << 16);
            }
        }
        __syncthreads();

        // ---- GEMM2: vlad[k][d] += a^T · x  (accumulate in regs across tiles) ----
#pragma unroll
        for (int ks = 0; ks < 2; ++ks) {
            half8 af = *(const half8*)&sat[w*16 + l15][ks*32 + quad*8];
#pragma unroll
            for (int nt = 0; nt < 8; ++nt) {
                half8 bf = *(const half8*)&sxt[nt*16 + l15][ks*32 + quad*8];
                acc2[nt] = __builtin_amdgcn_mfma_f32_16x16x32_f16(af, bf, acc2[nt], 0, 0, 0);
            }
        }
        // no barrier needed: next stage writes sx/sx2 only; sat/sxt rewritten
        // only after the next post-stage barrier.
    }

    // ---- colsum: reduce over this wave's columns, atomic to global ----
#pragma unroll
    for (int mt = 0; mt < 4; ++mt)
#pragma unroll
        for (int r = 0; r < 4; ++r) {
            float cs = csreg[mt][r];
            cs += __shfl_xor(cs, 1); cs += __shfl_xor(cs, 2);
            cs += __shfl_xor(cs, 4); cs += __shfl_xor(cs, 8);
            if (l15 == 0) atomicAdd(&colsum[b*KC + mt*16 + quad*4 + r], cs);
        }

    // ---- vlad partial -> global atomics ----
#pragma unroll
    for (int nt = 0; nt < 8; ++nt)
#pragma unroll
        for (int r = 0; r < 4; ++r) {
            int k = w*16 + quad*4 + r;
            int d = nt*16 + l15;
            atomicAdd(&vlad[((size_t)b*KC + k)*DD + d], acc2[nt][r]);
        }
}

// Phase 2: subtract colsum*c, L2-normalize per batch
__global__ __launch_bounds__(256)
void vlad_finalize(const float* __restrict__ vlad, const float* __restrict__ colsum,
                   const float* __restrict__ cg, float* __restrict__ out)
{
    __shared__ float red[4];
    const int b = blockIdx.x;
    const int tid = threadIdx.x;
    float v[32];
    float ss = 0.f;
#pragma unroll
    for (int i = 0; i < 32; ++i) {
        int idx = i*256 + tid;
        float val = vlad[(size_t)b*8192 + idx] - colsum[b*64 + (idx >> 7)] * cg[idx];
        v[i] = val;
        ss += val * val;
    }
#pragma unroll
    for (int m = 1; m < 64; m <<= 1) ss += __shfl_xor(ss, m);
    if ((tid & 63) == 0) red[tid >> 6] = ss;
    __syncthreads();
    float tot = red[0] + red[1] + red[2] + red[3];
    float scale = 1.0f / fmaxf(sqrtf(tot), 1e-12f);
#pragma unroll
    for (int i = 0; i < 32; ++i)
        out[(size_t)b*8192 + i*256 + tid] = v[i] * scale;
}

extern "C" void kernel_launch(void* const* d_in, const int* in_sizes, int n_in,
                              void* d_out, int out_size, void* d_ws, size_t ws_size,
                              hipStream_t stream)
{
    (void)in_sizes; (void)n_in; (void)out_size; (void)ws_size;
    const float* x = (const float*)d_in[0];
    const float* c = (const float*)d_in[1];
    float* out  = (float*)d_out;
    float* vlad = (float*)d_ws;                       // [32][64][128]
    float* cs   = vlad + (size_t)NB*KC*DD;            // [32][64]

    hipMemsetAsync(d_ws, 0, (size_t)(NB*KC*DD + NB*KC) * sizeof(float), stream);
    vlad_phase1<<<dim3(16, 32), 256, 0, stream>>>(x, c, vlad, cs);
    vlad_finalize<<<32, 256, 0, stream>>>(vlad, cs, c, out);
}

// Round 2
// 128.826 us; speedup vs baseline: 1.0532x; 1.0532x over previous
//
#include <hip/hip_runtime.h>

typedef _Float16 half8 __attribute__((ext_vector_type(8)));
typedef _Float16 half4_t __attribute__((ext_vector_type(4)));
typedef float floatx4 __attribute__((ext_vector_type(4)));

static constexpr int NB  = 32;    // batches
static constexpr int NP  = 4096;  // points per batch
static constexpr int DD  = 128;   // dim
static constexpr int KC  = 64;    // clusters
static constexpr int TN  = 64;    // points per tile
static constexpr int TPB = 4;     // tiles per block
static constexpr int SCP = 136;   // sclo pitch (halfwords), 16B-aligned rows
static constexpr int STP = 72;    // sxt / sat pitch (halfwords), 144B rows (16B-aligned)

#define ALPHA_  100.0f
#define LOG2E_  1.44269504088896f

// Phase 1: per (batch, 256-point group): distances -> softmax -> partial vlad.
// x feeds GEMM1 B-frags DIRECTLY from global (no LDS staging, no first barrier).
// x^T and a^T are written to swizzled LDS (col ^= quad<<4) -> conflict-free
// b16 writes and b128 reads. colsum comes from an extra MFMA vs a ones-column.
__global__ __launch_bounds__(256, 3)
void vlad_phase1(const float* __restrict__ xg, const float* __restrict__ cg,
                 float* __restrict__ vlad, float* __restrict__ colsum)
{
    __shared__ __align__(16) _Float16 sxt[DD][STP];   // x tile fp16 transposed [d][n^swz]
    __shared__ __align__(16) _Float16 sat[KC][STP];   // softmax a, transposed [k][n^swz]
    __shared__ __align__(16) _Float16 sclo[KC][SCP];  // centroid lo residual fp16 [k][d]
    __shared__ float sc2[KC];

    const int tid  = threadIdx.x;
    const int lane = tid & 63;
    const int w    = tid >> 6;    // wave 0..3
    const int l15  = lane & 15;
    const int quad = lane >> 4;
    const int b    = blockIdx.y;
    const float* xb = xg + (size_t)b * NP * DD;

    // ---- centroid prep: hi-frags in registers, lo tile + c2 in LDS ----
    half8 chi[4][4]; // [mt][ks]; lane holds C[mt*16+l15][ks*32+quad*8 .. +7]
#pragma unroll
    for (int mt = 0; mt < 4; ++mt)
#pragma unroll
        for (int ks = 0; ks < 4; ++ks) {
            const float* p = cg + (mt*16 + l15)*DD + ks*32 + quad*8;
            float4 a  = *(const float4*)p;
            float4 bb = *(const float4*)(p + 4);
            half8 h;
            h[0]=(_Float16)a.x;  h[1]=(_Float16)a.y;  h[2]=(_Float16)a.z;  h[3]=(_Float16)a.w;
            h[4]=(_Float16)bb.x; h[5]=(_Float16)bb.y; h[6]=(_Float16)bb.z; h[7]=(_Float16)bb.w;
            chi[mt][ks] = h;
        }
    {
        int k = tid >> 2, qq = tid & 3;
        const float* rp = cg + k*DD + qq*32;
        float c2p = 0.f;
#pragma unroll
        for (int j = 0; j < 8; ++j) {
            float4 v = *(const float4*)(rp + j*4);
            c2p += v.x*v.x + v.y*v.y + v.z*v.z + v.w*v.w;
            half4_t lo;
            lo[0] = (_Float16)(v.x - (float)(_Float16)v.x);
            lo[1] = (_Float16)(v.y - (float)(_Float16)v.y);
            lo[2] = (_Float16)(v.z - (float)(_Float16)v.z);
            lo[3] = (_Float16)(v.w - (float)(_Float16)v.w);
            *(half4_t*)&sclo[k][(qq*8 + j)*4] = lo;
        }
        c2p += __shfl_xor(c2p, 1);
        c2p += __shfl_xor(c2p, 2);
        if (qq == 0) sc2[k] = c2p;
    }
    __syncthreads();   // sclo / sc2 ready

    floatx4 acc2[8];   // vlad partial: row k = w*16+quad*4+r, col d = nt*16+l15
#pragma unroll
    for (int i = 0; i < 8; ++i) acc2[i] = (floatx4){0.f, 0.f, 0.f, 0.f};
    floatx4 accs = (floatx4){0.f, 0.f, 0.f, 0.f};  // colsum via ones-column MFMA

    // ones B-frag: B[point][col] = (col==0)
    half8 onesf;
#pragma unroll
    for (int j = 0; j < 8; ++j) onesf[j] = (_Float16)((l15 == 0) ? 1.0f : 0.0f);

    const int nloc = w*16 + l15;          // this lane's point within tile
    const int scol = nloc ^ (quad << 4);  // swizzled LDS column

    for (int tt = 0; tt < TPB; ++tt) {
        const int n0 = (blockIdx.x * TPB + tt) * TN;
        const float* xrow = xb + (size_t)(n0 + nloc) * DD + quad*8;

        // ---- direct global loads: 8 independent float4 (this lane's row segs) ----
        float4 fa[4], fb[4];
#pragma unroll
        for (int ks = 0; ks < 4; ++ks) {
            fa[ks] = *(const float4*)(xrow + ks*32);
            fb[ks] = *(const float4*)(xrow + ks*32 + 4);
        }

        float ssq = 0.f;
        floatx4 acc1[4];
#pragma unroll
        for (int mt = 0; mt < 4; ++mt) acc1[mt] = (floatx4){0.f, 0.f, 0.f, 0.f};

#pragma unroll
        for (int ks = 0; ks < 4; ++ks) {
            half8 xf;
            xf[0]=(_Float16)fa[ks].x; xf[1]=(_Float16)fa[ks].y;
            xf[2]=(_Float16)fa[ks].z; xf[3]=(_Float16)fa[ks].w;
            xf[4]=(_Float16)fb[ks].x; xf[5]=(_Float16)fb[ks].y;
            xf[6]=(_Float16)fb[ks].z; xf[7]=(_Float16)fb[ks].w;
            ssq += fa[ks].x*fa[ks].x + fa[ks].y*fa[ks].y + fa[ks].z*fa[ks].z + fa[ks].w*fa[ks].w
                 + fb[ks].x*fb[ks].x + fb[ks].y*fb[ks].y + fb[ks].z*fb[ks].z + fb[ks].w*fb[ks].w;
            // write x^T (swizzled): d = ks*32+quad*8+j  ->  (d>>3)&3 == quad
#pragma unroll
            for (int j = 0; j < 8; ++j)
                sxt[ks*32 + quad*8 + j][scol] = xf[j];
            // GEMM1: S^T[cluster][point] with c = hi + lo
#pragma unroll
            for (int mt = 0; mt < 4; ++mt) {
                half8 cl = *(const half8*)&sclo[mt*16 + l15][ks*32 + quad*8];
                acc1[mt] = __builtin_amdgcn_mfma_f32_16x16x32_f16(chi[mt][ks], xf, acc1[mt], 0, 0, 0);
                acc1[mt] = __builtin_amdgcn_mfma_f32_16x16x32_f16(cl,          xf, acc1[mt], 0, 0, 0);
            }
        }
        // full-row |x|^2: combine the 4 quads (same point, different d-segments)
        ssq += __shfl_xor(ssq, 16);
        ssq += __shfl_xor(ssq, 32);

        // ---- softmax over 64 clusters for this lane's point ----
        float dist[4][4];
#pragma unroll
        for (int mt = 0; mt < 4; ++mt) {
            floatx4 c2v = *(const floatx4*)&sc2[mt*16 + quad*4];
#pragma unroll
            for (int r = 0; r < 4; ++r) {
                float d2 = ssq + c2v[r] - 2.f*acc1[mt][r];
                dist[mt][r] = sqrtf(fmaxf(d2, 0.f));
            }
        }
        float dmin = dist[0][0];
#pragma unroll
        for (int mt = 0; mt < 4; ++mt)
#pragma unroll
            for (int r = 0; r < 4; ++r) dmin = fminf(dmin, dist[mt][r]);
        dmin = fminf(dmin, __shfl_xor(dmin, 16));
        dmin = fminf(dmin, __shfl_xor(dmin, 32));
        float pv[4][4];
        float psum = 0.f;
#pragma unroll
        for (int mt = 0; mt < 4; ++mt)
#pragma unroll
            for (int r = 0; r < 4; ++r) {
                float e = exp2f((dmin - dist[mt][r]) * (ALPHA_ * LOG2E_));
                pv[mt][r] = e; psum += e;
            }
        psum += __shfl_xor(psum, 16);
        psum += __shfl_xor(psum, 32);
        float invs = 1.0f / psum;
#pragma unroll
        for (int mt = 0; mt < 4; ++mt)
#pragma unroll
            for (int r = 0; r < 4; ++r) {
                // k = mt*16+quad*4+r -> (k>>2)&3 == quad -> same swizzled col
                sat[mt*16 + quad*4 + r][scol] = (_Float16)(pv[mt][r] * invs);
            }
        __syncthreads();   // sxt + sat visible

        // ---- GEMM2: vlad[k][d] += a^T · x ; colsum via ones column ----
#pragma unroll
        for (int ks2 = 0; ks2 < 2; ++ks2) {
            const int nbase = ks2*32 + quad*8;
            half8 af = *(const half8*)&sat[w*16 + l15][nbase ^ ((l15 >> 2) << 4)];
            accs = __builtin_amdgcn_mfma_f32_16x16x32_f16(af, onesf, accs, 0, 0, 0);
#pragma unroll
            for (int nt = 0; nt < 8; ++nt) {
                const int d = nt*16 + l15;
                half8 bf = *(const half8*)&sxt[d][nbase ^ (((d >> 3) & 3) << 4)];
                acc2[nt] = __builtin_amdgcn_mfma_f32_16x16x32_f16(af, bf, acc2[nt], 0, 0, 0);
            }
        }
        __syncthreads();   // reads done before next tile overwrites
    }

    // ---- epilogue: atomics into global accumulators ----
#pragma unroll
    for (int nt = 0; nt < 8; ++nt)
#pragma unroll
        for (int r = 0; r < 4; ++r) {
            int k = w*16 + quad*4 + r;
            int d = nt*16 + l15;
            atomicAdd(&vlad[((size_t)b*KC + k)*DD + d], acc2[nt][r]);
        }
    if (l15 == 0) {
#pragma unroll
        for (int r = 0; r < 4; ++r)
            atomicAdd(&colsum[b*KC + w*16 + quad*4 + r], accs[r]);
    }
}

// Phase 2: subtract colsum*c, L2-normalize per batch
__global__ __launch_bounds__(256)
void vlad_finalize(const float* __restrict__ vlad, const float* __restrict__ colsum,
                   const float* __restrict__ cg, float* __restrict__ out)
{
    __shared__ float red[4];
    const int b = blockIdx.x;
    const int tid = threadIdx.x;
    float v[32];
    float ss = 0.f;
#pragma unroll
    for (int i = 0; i < 32; ++i) {
        int idx = i*256 + tid;
        float val = vlad[(size_t)b*8192 + idx] - colsum[b*64 + (idx >> 7)] * cg[idx];
        v[i] = val;
        ss += val * val;
    }
#pragma unroll
    for (int m = 1; m < 64; m <<= 1) ss += __shfl_xor(ss, m);
    if ((tid & 63) == 0) red[tid >> 6] = ss;
    __syncthreads();
    float tot = red[0] + red[1] + red[2] + red[3];
    float scale = 1.0f / fmaxf(sqrtf(tot), 1e-12f);
#pragma unroll
    for (int i = 0; i < 32; ++i)
        out[(size_t)b*8192 + i*256 + tid] = v[i] * scale;
}

extern "C" void kernel_launch(void* const* d_in, const int* in_sizes, int n_in,
                              void* d_out, int out_size, void* d_ws, size_t ws_size,
                              hipStream_t stream)
{
    (void)in_sizes; (void)n_in; (void)out_size; (void)ws_size;
    const float* x = (const float*)d_in[0];
    const float* c = (const float*)d_in[1];
    float* out  = (float*)d_out;
    float* vlad = (float*)d_ws;                       // [32][64][128]
    float* cs   = vlad + (size_t)NB*KC*DD;            // [32][64]

    hipMemsetAsync(d_ws, 0, (size_t)(NB*KC*DD + NB*KC) * sizeof(float), stream);
    vlad_phase1<<<dim3(16, 32), 256, 0, stream>>>(x, c, vlad, cs);
    vlad_finalize<<<32, 256, 0, stream>>>(vlad, cs, c, out);
}